// Round 4
// baseline (253.325 us; speedup 1.0000x reference)
//
#include <hip/hip_runtime.h>
#include <hip/hip_bf16.h>

#define SEQ 2048
#define EMB 2048
#define NH 16
#define WIN 256
#define HD 128
#define KDIM 2048
#define NDIM 2048

typedef __bf16 bf16x8 __attribute__((ext_vector_type(8)));
typedef float f32x4 __attribute__((ext_vector_type(4)));

__device__ __forceinline__ ushort f2bf(float f) {
  unsigned int x = __float_as_uint(f);
  unsigned int r = (x + 0x7fffu + ((x >> 16) & 1u)) >> 16;
  return (ushort)r;
}

__device__ __forceinline__ void gl16(const ushort* g, ushort* l) {
  __builtin_amdgcn_global_load_lds(
      (const __attribute__((address_space(1))) ushort*)g,
      (__attribute__((address_space(3))) ushort*)l, 16, 0, 0);
}

#define MFMA __builtin_amdgcn_mfma_f32_16x16x32_bf16
#define BAR __builtin_amdgcn_s_barrier
#define PRIO __builtin_amdgcn_s_setprio

// ---------------- x f32 -> bf16 (once) --------------------------------------
__global__ __launch_bounds__(256) void xconv_kernel(
    const float* __restrict__ x, ushort* __restrict__ xb) {
  size_t i = ((size_t)blockIdx.x * 256 + threadIdx.x) * 8;
  float4 f0 = *(const float4*)&x[i];
  float4 f1 = *(const float4*)&x[i + 4];
  union { ushort u[8]; uint4 v; } pk;
  pk.u[0] = f2bf(f0.x); pk.u[1] = f2bf(f0.y);
  pk.u[2] = f2bf(f0.z); pk.u[3] = f2bf(f0.w);
  pk.u[4] = f2bf(f1.x); pk.u[5] = f2bf(f1.y);
  pk.u[6] = f2bf(f1.z); pk.u[7] = f2bf(f1.w);
  *(uint4*)&xb[i] = pk.v;
}

// ---------------- W transpose: f32 [K][N] -> blocked swizzled bf16 tiles ----
// 128-row x 64-k tiles, 8192 ush each; tileIdx = ((mat*16+nb)*32 + kblk).
// slot s (r=s>>3, kc=s&7) holds W[k0 + (kc^(r&7))*8 + j][nb*128 + r].
__global__ __launch_bounds__(256) void wtrans_kernel(
    const float* __restrict__ w0, const float* __restrict__ w1,
    const float* __restrict__ w2, const float* __restrict__ w3,
    ushort* __restrict__ wt) {
  __shared__ __align__(16) float tf[64 * 132];
  const int t = threadIdx.x;
  const int nb = blockIdx.x, kblk = blockIdx.y, mat = blockIdx.z;
  const float* Wp = mat == 0 ? w0 : mat == 1 ? w1 : mat == 2 ? w2 : w3;
  const int n0 = nb * 128, k0 = kblk * 64;
#pragma unroll
  for (int p = 0; p < 8; ++p) {
    int kk = (t >> 5) + 8 * p;
    int nn = (t & 31) * 4;
    float4 v = *(const float4*)&Wp[(size_t)(k0 + kk) * NDIM + n0 + nn];
    *(float4*)&tf[kk * 132 + nn] = v;
  }
  __syncthreads();
  ushort* dst = wt + (size_t)((mat * 16 + nb) * 32 + kblk) * 8192;
#pragma unroll
  for (int p = 0; p < 4; ++p) {
    int s = p * 256 + t;
    int r = s >> 3, kc = s & 7;
    int cg = kc ^ (r & 7);
    union { ushort u[8]; uint4 v; } pk;
#pragma unroll
    for (int j = 0; j < 8; ++j) pk.u[j] = f2bf(tf[(cg * 8 + j) * 132 + r]);
    *(uint4*)&dst[s * 8] = pk.v;
  }
}

// ---------------- QKV GEMM: 256x256 tile, BK=64, 8 waves, 4-phase ----------
// m201-faithful: 2-dbuf, 16-MFMA clusters, per-phase ds||stage interleave,
// raw barriers, counted vmcnt(8) once per K-tile, setprio.
__global__ __launch_bounds__(512, 2) void gemm_qkv_kernel(
    const ushort* __restrict__ Ab, const ushort* __restrict__ Wt,
    const float* __restrict__ bq, const float* __restrict__ bk,
    const float* __restrict__ bv, float* __restrict__ outF,
    ushort* __restrict__ outQ) {
  __shared__ __align__(16) ushort L[65536];  // A[2][16384] | B[2][16384]
  const int t = threadIdx.x;
  const int w = t >> 6, lane = t & 63;
  const int l15 = lane & 15, lg = lane >> 4;
  const int wm = w >> 2, wn = w & 3;  // 2M x 4N waves, wave-tile 128x64
  const int bid = blockIdx.x;                    // 0..383
  const int wkid = (bid & 7) * 48 + (bid >> 3);  // bijective (384 = 8*48)
  const int mblk = wkid & 15, nb = wkid >> 4;    // nb 0..23 over fused N=6144
  const int m0 = mblk * 256;
  const ushort* wbase = Wt + (size_t)nb * 524288;  // two 128-tiles * 32 kt

  const ushort* aS[4];
#pragma unroll
  for (int j = 0; j < 4; ++j) {
    int s = j * 512 + t;
    int r = s >> 3, kc = s & 7;
    aS[j] = Ab + (size_t)(m0 + r) * KDIM + (kc ^ (r & 7)) * 8;
  }
  const ushort* bS[4];
  bS[0] = wbase + (size_t)t * 8;
  bS[1] = wbase + (size_t)(t + 512) * 8;
  bS[2] = wbase + 262144 + (size_t)t * 8;
  bS[3] = wbase + 262144 + (size_t)(t + 512) * 8;

  f32x4 acc[8][4] = {};

#define STAGE_A(kt, buf)                                        \
  { ushort* d = &L[(buf) * 16384 + w * 512];                    \
    gl16(aS[0] + (kt) * 64, d);                                 \
    gl16(aS[1] + (kt) * 64, d + 4096);                          \
    gl16(aS[2] + (kt) * 64, d + 8192);                          \
    gl16(aS[3] + (kt) * 64, d + 12288); }
#define STAGE_B(kt, buf)                                        \
  { ushort* d = &L[32768 + (buf) * 16384 + w * 512];            \
    gl16(bS[0] + (kt) * 8192, d);                               \
    gl16(bS[1] + (kt) * 8192, d + 4096);                        \
    gl16(bS[2] + (kt) * 8192, d + 8192);                        \
    gl16(bS[3] + (kt) * 8192, d + 12288); }

  const int NT = 32;
  STAGE_A(0, 0) STAGE_B(0, 0) STAGE_A(1, 1) STAGE_B(1, 1)
  asm volatile("s_waitcnt vmcnt(8)" ::: "memory");
  BAR();

  for (int tk = 0; tk < NT; ++tk) {
    const int buf = tk & 1;
    const int ts = (tk + 2 < NT) ? tk + 2 : NT - 1;  // tail: idempotent restage
    const ushort* Ar = &L[buf * 16384];
    const ushort* Br = &L[32768 + buf * 16384];
    bf16x8 a0[8], a1[8], bb[4];
    // ---- Ph1: ds A(kk0) x8 + B(kk0,ni0/1); MFMA kk0 ni0/1 ----
#pragma unroll
    for (int mi = 0; mi < 8; ++mi) {
      int row = wm * 128 + mi * 16 + l15;
      a0[mi] = *(const bf16x8*)&Ar[row * 64 + ((lg ^ (row & 7)) * 8)];
    }
    {
      int r0 = wn * 64 + l15, r1 = r0 + 16;
      bb[0] = *(const bf16x8*)&Br[r0 * 64 + ((lg ^ (r0 & 7)) * 8)];
      bb[1] = *(const bf16x8*)&Br[r1 * 64 + ((lg ^ (r1 & 7)) * 8)];
    }
    BAR(); PRIO(1);
#pragma unroll
    for (int mi = 0; mi < 8; ++mi) acc[mi][0] = MFMA(a0[mi], bb[0], acc[mi][0], 0, 0, 0);
#pragma unroll
    for (int mi = 0; mi < 8; ++mi) acc[mi][1] = MFMA(a0[mi], bb[1], acc[mi][1], 0, 0, 0);
    PRIO(0); BAR();
    // ---- Ph2: ds B(kk0,ni2/3) + A(kk1) x8; MFMA kk0 ni2/3 ----
    {
      int r2 = wn * 64 + 32 + l15, r3 = r2 + 16;
      bb[2] = *(const bf16x8*)&Br[r2 * 64 + ((lg ^ (r2 & 7)) * 8)];
      bb[3] = *(const bf16x8*)&Br[r3 * 64 + ((lg ^ (r3 & 7)) * 8)];
    }
#pragma unroll
    for (int mi = 0; mi < 8; ++mi) {
      int row = wm * 128 + mi * 16 + l15;
      a1[mi] = *(const bf16x8*)&Ar[row * 64 + (((4 + lg) ^ (row & 7)) * 8)];
    }
    BAR(); PRIO(1);
#pragma unroll
    for (int mi = 0; mi < 8; ++mi) acc[mi][2] = MFMA(a0[mi], bb[2], acc[mi][2], 0, 0, 0);
#pragma unroll
    for (int mi = 0; mi < 8; ++mi) acc[mi][3] = MFMA(a0[mi], bb[3], acc[mi][3], 0, 0, 0);
    PRIO(0); BAR();
    // ---- Ph3: ds B(kk1,ni0/1); stage A(tk+2); MFMA kk1 ni0/1 ----
    {
      int r0 = wn * 64 + l15, r1 = r0 + 16;
      bb[0] = *(const bf16x8*)&Br[r0 * 64 + (((4 + lg) ^ (r0 & 7)) * 8)];
      bb[1] = *(const bf16x8*)&Br[r1 * 64 + (((4 + lg) ^ (r1 & 7)) * 8)];
    }
    STAGE_A(ts, buf)
    BAR(); PRIO(1);
#pragma unroll
    for (int mi = 0; mi < 8; ++mi) acc[mi][0] = MFMA(a1[mi], bb[0], acc[mi][0], 0, 0, 0);
#pragma unroll
    for (int mi = 0; mi < 8; ++mi) acc[mi][1] = MFMA(a1[mi], bb[1], acc[mi][1], 0, 0, 0);
    PRIO(0); BAR();
    // ---- Ph4: ds B(kk1,ni2/3); stage B(tk+2); MFMA kk1 ni2/3; vmcnt(8) ----
    {
      int r2 = wn * 64 + 32 + l15, r3 = r2 + 16;
      bb[2] = *(const bf16x8*)&Br[r2 * 64 + (((4 + lg) ^ (r2 & 7)) * 8)];
      bb[3] = *(const bf16x8*)&Br[r3 * 64 + (((4 + lg) ^ (r3 & 7)) * 8)];
    }
    STAGE_B(ts, buf)
    BAR(); PRIO(1);
#pragma unroll
    for (int mi = 0; mi < 8; ++mi) acc[mi][2] = MFMA(a1[mi], bb[2], acc[mi][2], 0, 0, 0);
#pragma unroll
    for (int mi = 0; mi < 8; ++mi) acc[mi][3] = MFMA(a1[mi], bb[3], acc[mi][3], 0, 0, 0);
    PRIO(0);
    asm volatile("s_waitcnt vmcnt(8)" ::: "memory");
    BAR();
  }
#undef STAGE_A
#undef STAGE_B

  const int z = nb >> 3;
  const float* bias = z == 0 ? bq : z == 1 ? bk : bv;
#pragma unroll
  for (int ni = 0; ni < 4; ++ni) {
    int nl = wn * 64 + ni * 16 + l15;
    int n6 = (nb & 7) * 256 + nl;          // 0..2047 within matrix
    float bvv = bias[n6];
    int h = n6 >> 7, d = n6 & 127;
#pragma unroll
    for (int mi = 0; mi < 8; ++mi) {
#pragma unroll
      for (int r = 0; r < 4; ++r) {
        int m = m0 + wm * 128 + mi * 16 + lg * 4 + r;
        float val = acc[mi][ni][r] + bvv;
        int b = m >> 11, s = m & 2047;
        size_t idx = (((size_t)b * NH + h) * SEQ + s) * HD + d;
        if (z == 0) outQ[idx] = f2bf(val);
        else if (z == 1) outF[(size_t)8388608u + idx] = val;
        else outF[(size_t)16777216u + idx] = val;
      }
    }
  }
}

// ---------------- out-proj GEMM: 256x128 tile, BK=64, 2-phase --------------
__global__ __launch_bounds__(512, 2) void gemm_out_kernel(
    const ushort* __restrict__ Ab, const ushort* __restrict__ Wt,
    const float* __restrict__ bo, float* __restrict__ outF) {
  __shared__ __align__(16) ushort L[49152];  // A[2][16384] | B[2][8192]
  const int t = threadIdx.x;
  const int w = t >> 6, lane = t & 63;
  const int l15 = lane & 15, lg = lane >> 4;
  const int wm = w >> 1, wn = w & 1;  // 4M x 2N waves, wave-tile 64x64
  const int bid = blockIdx.x;                    // 0..255
  const int wkid = (bid & 7) * 32 + (bid >> 3);
  const int mblk = wkid & 15, nb = wkid >> 4;    // nb 0..15 (128-wide)
  const int m0 = mblk * 256;
  const ushort* wbase = Wt + (size_t)(48 + nb) * 262144;  // Wo 128-tiles

  const ushort* aS[4];
#pragma unroll
  for (int j = 0; j < 4; ++j) {
    int s = j * 512 + t;
    int r = s >> 3, kc = s & 7;
    aS[j] = Ab + (size_t)(m0 + r) * KDIM + (kc ^ (r & 7)) * 8;
  }
  const ushort* bS[2];
  bS[0] = wbase + (size_t)t * 8;
  bS[1] = wbase + (size_t)(t + 512) * 8;

  f32x4 acc[4][4] = {};

#define STAGE_A(kt, buf)                                        \
  { ushort* d = &L[(buf) * 16384 + w * 512];                    \
    gl16(aS[0] + (kt) * 64, d);                                 \
    gl16(aS[1] + (kt) * 64, d + 4096);                          \
    gl16(aS[2] + (kt) * 64, d + 8192);                          \
    gl16(aS[3] + (kt) * 64, d + 12288); }
#define STAGE_B(kt, buf)                                        \
  { ushort* d = &L[32768 + (buf) * 8192 + w * 512];             \
    gl16(bS[0] + (kt) * 8192, d);                               \
    gl16(bS[1] + (kt) * 8192, d + 4096); }

  const int NT = 32;
  STAGE_A(0, 0) STAGE_B(0, 0) STAGE_A(1, 1) STAGE_B(1, 1)
  asm volatile("s_waitcnt vmcnt(6)" ::: "memory");
  BAR();

  for (int tk = 0; tk < NT; ++tk) {
    const int buf = tk & 1;
    const int ts = (tk + 2 < NT) ? tk + 2 : NT - 1;
    const ushort* Ar = &L[buf * 16384];
    const ushort* Br = &L[32768 + buf * 8192];
    bf16x8 af[4], bf[4];
    // ---- Ph1: kk0 ----
#pragma unroll
    for (int mi = 0; mi < 4; ++mi) {
      int row = wm * 64 + mi * 16 + l15;
      af[mi] = *(const bf16x8*)&Ar[row * 64 + ((lg ^ (row & 7)) * 8)];
    }
#pragma unroll
    for (int ni = 0; ni < 4; ++ni) {
      int row = wn * 64 + ni * 16 + l15;
      bf[ni] = *(const bf16x8*)&Br[row * 64 + ((lg ^ (row & 7)) * 8)];
    }
    BAR(); PRIO(1);
#pragma unroll
    for (int mi = 0; mi < 4; ++mi)
#pragma unroll
      for (int ni = 0; ni < 4; ++ni)
        acc[mi][ni] = MFMA(af[mi], bf[ni], acc[mi][ni], 0, 0, 0);
    PRIO(0); BAR();
    // ---- Ph2: kk1; stage t+2 after MFMA; vmcnt(6) ----
#pragma unroll
    for (int mi = 0; mi < 4; ++mi) {
      int row = wm * 64 + mi * 16 + l15;
      af[mi] = *(const bf16x8*)&Ar[row * 64 + (((4 + lg) ^ (row & 7)) * 8)];
    }
#pragma unroll
    for (int ni = 0; ni < 4; ++ni) {
      int row = wn * 64 + ni * 16 + l15;
      bf[ni] = *(const bf16x8*)&Br[row * 64 + (((4 + lg) ^ (row & 7)) * 8)];
    }
    BAR(); PRIO(1);
#pragma unroll
    for (int mi = 0; mi < 4; ++mi)
#pragma unroll
      for (int ni = 0; ni < 4; ++ni)
        acc[mi][ni] = MFMA(af[mi], bf[ni], acc[mi][ni], 0, 0, 0);
    PRIO(0);
    STAGE_A(ts, buf)
    STAGE_B(ts, buf)
    asm volatile("s_waitcnt vmcnt(6)" ::: "memory");
    BAR();
  }
#undef STAGE_A
#undef STAGE_B

#pragma unroll
  for (int ni = 0; ni < 4; ++ni) {
    int n = nb * 128 + wn * 64 + ni * 16 + l15;
    float bvv = bo[n];
#pragma unroll
    for (int mi = 0; mi < 4; ++mi) {
#pragma unroll
      for (int r = 0; r < 4; ++r) {
        int m = m0 + wm * 64 + mi * 16 + lg * 4 + r;
        outF[(size_t)m * NDIM + n] = acc[mi][ni][r] + bvv;
      }
    }
  }
}

// ---------------- sliding-window flash attention (unchanged) ---------------
__global__ __launch_bounds__(256) void attn_kernel(
    const ushort* __restrict__ Qb, const float* __restrict__ Kf,
    const float* __restrict__ Vf, ushort* __restrict__ ctx) {
  __shared__ __align__(16) ushort Kl[64 * 128];
  __shared__ __align__(16) ushort Vl[128 * 72];
  __shared__ __align__(16) ushort Pl[4 * 16 * 72];
  const int t = threadIdx.x;
  const int bh = blockIdx.x;
  const int q0 = blockIdx.y * 64;
  const int lane = t & 63, w = t >> 6;
  const int l15 = lane & 15, lg = lane >> 4;
  const int b = bh >> 4, h = bh & 15;
  const ushort* Qbase = Qb + (size_t)bh * SEQ * HD;
  const float* Kbase = Kf + (size_t)bh * SEQ * HD;
  const float* Vbase = Vf + (size_t)bh * SEQ * HD;

  bf16x8 aq[4];
#pragma unroll
  for (int ds = 0; ds < 4; ++ds)
    aq[ds] = *(const bf16x8*)&Qbase[(size_t)(q0 + w * 16 + l15) * HD + ds * 32 + lg * 8];

  f32x4 accc[8] = {};
  float mrow[4], lrow[4];
#pragma unroll
  for (int r = 0; r < 4; ++r) { mrow[r] = -1e30f; lrow[r] = 0.f; }

  int ktlo = (q0 - WIN + 1) >> 6;
  if (ktlo < 0) ktlo = 0;
  const int kthi = q0 >> 6;

  for (int kt = ktlo; kt <= kthi; ++kt) {
    __syncthreads();
#pragma unroll
    for (int p = 0; p < 4; ++p) {
      int idx = p * 256 + t;
      int row = idx >> 4, cs = idx & 15;
      int c = cs ^ (row & 7);
      const float* sp = &Kbase[(size_t)(kt * 64 + row) * HD + c * 8];
      float4 f0 = *(const float4*)sp;
      float4 f1 = *(const float4*)(sp + 4);
      union { ushort u[8]; uint4 v; } pk;
      pk.u[0] = f2bf(f0.x); pk.u[1] = f2bf(f0.y);
      pk.u[2] = f2bf(f0.z); pk.u[3] = f2bf(f0.w);
      pk.u[4] = f2bf(f1.x); pk.u[5] = f2bf(f1.y);
      pk.u[6] = f2bf(f1.z); pk.u[7] = f2bf(f1.w);
      *(uint4*)&Kl[row * 128 + cs * 8] = pk.v;
    }
#pragma unroll
    for (int p = 0; p < 4; ++p) {
      int idx = p * 256 + t;
      int key = idx & 63, dc = idx >> 6;
      const float* sp = &Vbase[(size_t)(kt * 64 + key) * HD + dc * 8];
      float4 f0 = *(const float4*)sp;
      float4 f1 = *(const float4*)(sp + 4);
      Vl[(dc * 8 + 0) * 72 + key] = f2bf(f0.x);
      Vl[(dc * 8 + 1) * 72 + key] = f2bf(f0.y);
      Vl[(dc * 8 + 2) * 72 + key] = f2bf(f0.z);
      Vl[(dc * 8 + 3) * 72 + key] = f2bf(f0.w);
      Vl[(dc * 8 + 4) * 72 + key] = f2bf(f1.x);
      Vl[(dc * 8 + 5) * 72 + key] = f2bf(f1.y);
      Vl[(dc * 8 + 6) * 72 + key] = f2bf(f1.z);
      Vl[(dc * 8 + 7) * 72 + key] = f2bf(f1.w);
    }
    __syncthreads();

    f32x4 sacc[4] = {};
#pragma unroll
    for (int ds = 0; ds < 4; ++ds) {
#pragma unroll
      for (int kf = 0; kf < 4; ++kf) {
        int key = kf * 16 + l15;
        bf16x8 kb = *(const bf16x8*)&Kl[key * 128 + (((ds * 4 + lg) ^ (key & 7)) * 8)];
        sacc[kf] = MFMA(aq[ds], kb, sacc[kf], 0, 0, 0);
      }
    }

    const float scale = 0.08838834764831845f;
    const float L2E = 1.4426950408889634f;
#pragma unroll
    for (int r = 0; r < 4; ++r) {
      int q = q0 + w * 16 + lg * 4 + r;
      float sv[4];
      float mx = -1e30f;
#pragma unroll
      for (int kf = 0; kf < 4; ++kf) {
        int key = kt * 64 + kf * 16 + l15;
        float s = sacc[kf][r] * scale;
        bool valid = (key <= q) && (key + WIN > q);
        s = valid ? s : -1e30f;
        sv[kf] = s;
        mx = fmaxf(mx, s);
      }
      mx = fmaxf(mx, __shfl_xor(mx, 1));
      mx = fmaxf(mx, __shfl_xor(mx, 2));
      mx = fmaxf(mx, __shfl_xor(mx, 4));
      mx = fmaxf(mx, __shfl_xor(mx, 8));
      float mnew = fmaxf(mrow[r], mx);
      float sf = exp2f((mrow[r] - mnew) * L2E);
      float ps = 0.f;
#pragma unroll
      for (int kf = 0; kf < 4; ++kf) {
        float p = (sv[kf] > -1e29f) ? exp2f((sv[kf] - mnew) * L2E) : 0.f;
        ps += p;
        Pl[w * 1152 + (lg * 4 + r) * 72 + kf * 16 + l15] = f2bf(p);
      }
      ps += __shfl_xor(ps, 1);
      ps += __shfl_xor(ps, 2);
      ps += __shfl_xor(ps, 4);
      ps += __shfl_xor(ps, 8);
      lrow[r] = lrow[r] * sf + ps;
      mrow[r] = mnew;
#pragma unroll
      for (int nf = 0; nf < 8; ++nf) accc[nf][r] *= sf;
    }

#pragma unroll
    for (int ks = 0; ks < 2; ++ks) {
      bf16x8 pa = *(const bf16x8*)&Pl[w * 1152 + l15 * 72 + ks * 32 + lg * 8];
#pragma unroll
      for (int nf = 0; nf < 8; ++nf) {
        bf16x8 vb = *(const bf16x8*)&Vl[(nf * 16 + l15) * 72 + ks * 32 + lg * 8];
        accc[nf] = MFMA(pa, vb, accc[nf], 0, 0, 0);
      }
    }
  }

#pragma unroll
  for (int r = 0; r < 4; ++r) {
    int q = q0 + w * 16 + lg * 4 + r;
    float inv = 1.0f / lrow[r];
    size_t rowoff = ((size_t)b * SEQ + q) * EMB + (size_t)h * HD;
#pragma unroll
    for (int nf = 0; nf < 8; ++nf)
      ctx[rowoff + nf * 16 + l15] = f2bf(accc[nf][r] * inv);
  }
}

// ---------------------------------------------------------------------------
extern "C" void kernel_launch(void* const* d_in, const int* in_sizes, int n_in,
                              void* d_out, int out_size, void* d_ws, size_t ws_size,
                              hipStream_t stream) {
  const float* x  = (const float*)d_in[0];
  const float* Wq = (const float*)d_in[1];
  const float* bq = (const float*)d_in[2];
  const float* Wk = (const float*)d_in[3];
  const float* bk = (const float*)d_in[4];
  const float* Wv = (const float*)d_in[5];
  const float* bv = (const float*)d_in[6];
  const float* Wo = (const float*)d_in[7];
  const float* bo = (const float*)d_in[8];
  float* out = (float*)d_out;
  ushort* ws = (ushort*)d_ws;
  // ws (ushort elems): Wt 16777216 | Qb 8388608 | xb/ctx 8388608 (aliased)
  ushort* Wt   = ws;
  ushort* Qb   = ws + 16777216;
  ushort* xb   = ws + 25165824;
  ushort* ctxb = xb;

  xconv_kernel<<<4096, 256, 0, stream>>>(x, xb);
  wtrans_kernel<<<dim3(16, 32, 4), 256, 0, stream>>>(Wq, Wk, Wv, Wo, Wt);
  gemm_qkv_kernel<<<384, 512, 0, stream>>>(xb, Wt, bq, bk, bv, out, Qb);
  attn_kernel<<<dim3(32, 32), 256, 0, stream>>>(Qb, out + 8388608, out + 16777216, ctxb);
  gemm_out_kernel<<<256, 512, 0, stream>>>(ctxb, Wt, bo, out);
}

// Round 5
// 248.282 us; speedup vs baseline: 1.0203x; 1.0203x over previous
//
#include <hip/hip_runtime.h>
#include <hip/hip_bf16.h>

#define SEQ 2048
#define EMB 2048
#define NH 16
#define WIN 256
#define HD 128
#define KDIM 2048
#define NDIM 2048

typedef __bf16 bf16x8 __attribute__((ext_vector_type(8)));
typedef float f32x4 __attribute__((ext_vector_type(4)));

#define MFMA __builtin_amdgcn_mfma_f32_16x16x32_bf16
#define BAR __builtin_amdgcn_s_barrier

__device__ __forceinline__ ushort f2bf(float f) {
  unsigned int x = __float_as_uint(f);
  unsigned int r = (x + 0x7fffu + ((x >> 16) & 1u)) >> 16;
  return (ushort)r;
}

__device__ __forceinline__ void gl16(const ushort* g, ushort* l) {
  // async global->LDS, 16B/lane; LDS dest = wave-uniform base + lane*16
  __builtin_amdgcn_global_load_lds(
      (const __attribute__((address_space(1))) ushort*)g,
      (__attribute__((address_space(3))) ushort*)l, 16, 0, 0);
}

// ---------------- x f32 -> bf16 (once) --------------------------------------
__global__ __launch_bounds__(256) void xconv_kernel(
    const float* __restrict__ x, ushort* __restrict__ xb) {
  size_t i = ((size_t)blockIdx.x * 256 + threadIdx.x) * 8;
  float4 f0 = *(const float4*)&x[i];
  float4 f1 = *(const float4*)&x[i + 4];
  union { ushort u[8]; uint4 v; } pk;
  pk.u[0] = f2bf(f0.x); pk.u[1] = f2bf(f0.y);
  pk.u[2] = f2bf(f0.z); pk.u[3] = f2bf(f0.w);
  pk.u[4] = f2bf(f1.x); pk.u[5] = f2bf(f1.y);
  pk.u[6] = f2bf(f1.z); pk.u[7] = f2bf(f1.w);
  *(uint4*)&xb[i] = pk.v;
}

// ---------------- W transpose: f32 [K][N] -> blocked swizzled bf16 tiles ----
// tile (nblk,kblk): 128 n-rows x 32 k, 4096 elems contiguous.
// row r, stored chunk cs holds logical k-chunk cs ^ ((r>>1)&3)
__global__ __launch_bounds__(256) void wtrans_kernel(
    const float* __restrict__ w0, const float* __restrict__ w1,
    const float* __restrict__ w2, const float* __restrict__ w3,
    ushort* __restrict__ wt) {
  __shared__ __align__(16) float tf[32 * 132];
  const int t = threadIdx.x;
  const int nblk = blockIdx.x, kblk = blockIdx.y, mat = blockIdx.z;
  const float* Wp = mat == 0 ? w0 : mat == 1 ? w1 : mat == 2 ? w2 : w3;
  const int n0 = nblk * 128, k0 = kblk * 32;
#pragma unroll
  for (int p = 0; p < 4; ++p) {
    int kk = (t >> 5) + 8 * p;
    int nn = (t & 31) * 4;
    float4 v = *(const float4*)&Wp[(size_t)(k0 + kk) * NDIM + n0 + nn];
    *(float4*)&tf[kk * 132 + nn] = v;
  }
  __syncthreads();
  ushort* dst = wt + (size_t)mat * ((size_t)NDIM * KDIM) +
                (size_t)(nblk * 64 + kblk) * 4096;
#pragma unroll
  for (int p = 0; p < 2; ++p) {
    int idx = p * 256 + t;
    int r = idx >> 2, cs = idx & 3;
    int c = cs ^ ((r >> 1) & 3);
    union { ushort u[8]; uint4 v; } pk;
#pragma unroll
    for (int j = 0; j < 8; ++j) pk.u[j] = f2bf(tf[(c * 8 + j) * 132 + r]);
    *(uint4*)&dst[idx * 8] = pk.v;
  }
}

// ---------------- GEMM (R2-verified m97 structure) -------------------------
// 128x128 tile, BK=32, 4 waves. MODE 1: QKV fused; also emits bf16 K and
// bf16 V^T for the attention kernel. MODE 0: out proj.
template <int MODE>
__global__ __launch_bounds__(256) void gemm_kernel(
    const ushort* __restrict__ Ab, const ushort* __restrict__ Wt,
    const float* __restrict__ b0, const float* __restrict__ b1,
    const float* __restrict__ b2, float* __restrict__ outF,
    ushort* __restrict__ outQ, ushort* __restrict__ Kbf,
    ushort* __restrict__ vTb) {
  __shared__ __align__(16) ushort As[128 * 32];
  __shared__ __align__(16) ushort Bs[128 * 32];
  const int t = threadIdx.x;
  const int mblk = blockIdx.x, nblk = blockIdx.y, z = blockIdx.z;
  const int m0 = mblk * 128, n0 = nblk * 128;
  const ushort* wtile = Wt + (size_t)z * ((size_t)NDIM * KDIM) +
                        (size_t)(nblk * 64) * 4096;
  const int lane = t & 63, wid = t >> 6;
  const int l15 = lane & 15, lg = lane >> 4;
  const int wm = wid >> 1, wn = wid & 1;
  f32x4 acc[4][4] = {};

  const int slot0 = wid * 128 + lane;
  const int slot1 = slot0 + 64;
  const int r0 = slot0 >> 2, c0 = (slot0 & 3) ^ ((r0 >> 1) & 3);
  const int r1 = slot1 >> 2, c1 = (slot1 & 3) ^ ((r1 >> 1) & 3);
  const ushort* aS0 = Ab + (size_t)(m0 + r0) * KDIM + c0 * 8;
  const ushort* aS1 = Ab + (size_t)(m0 + r1) * KDIM + c1 * 8;
  const ushort* bS0 = wtile + slot0 * 8;
  const ushort* bS1 = wtile + slot1 * 8;
  ushort* aD0 = &As[(wid * 128) * 8];
  ushort* aD1 = &As[(wid * 128 + 64) * 8];
  ushort* bD0 = &Bs[(wid * 128) * 8];
  ushort* bD1 = &Bs[(wid * 128 + 64) * 8];

  for (int kt = 0; kt < KDIM / 32; ++kt) {
    __syncthreads();
    gl16(aS0, aD0); gl16(aS1, aD1);
    gl16(bS0, bD0); gl16(bS1, bD1);
    aS0 += 32; aS1 += 32; bS0 += 4096; bS1 += 4096;
    __syncthreads();
    bf16x8 af[4], bfr[4];
#pragma unroll
    for (int mf = 0; mf < 4; ++mf) {
      int r = wm * 64 + mf * 16 + l15;
      af[mf] = *(const bf16x8*)&As[r * 32 + ((lg ^ ((r >> 1) & 3)) * 8)];
    }
#pragma unroll
    for (int nf = 0; nf < 4; ++nf) {
      int r = wn * 64 + nf * 16 + l15;
      bfr[nf] = *(const bf16x8*)&Bs[r * 32 + ((lg ^ ((r >> 1) & 3)) * 8)];
    }
#pragma unroll
    for (int mf = 0; mf < 4; ++mf)
#pragma unroll
      for (int nf = 0; nf < 4; ++nf)
        acc[mf][nf] = MFMA(af[mf], bfr[nf], acc[mf][nf], 0, 0, 0);
  }

  const float* bias = (MODE == 0) ? b0 : (z == 0 ? b0 : z == 1 ? b1 : b2);
#pragma unroll
  for (int nf = 0; nf < 4; ++nf) {
    int nl = wn * 64 + nf * 16 + l15;
    int n = n0 + nl;
    float bv = bias[n];
#pragma unroll
    for (int mf = 0; mf < 4; ++mf) {
      if (MODE == 0) {
#pragma unroll
        for (int r = 0; r < 4; ++r) {
          int m = m0 + wm * 64 + mf * 16 + lg * 4 + r;
          outF[(size_t)m * NDIM + n] = acc[mf][nf][r] + bv;
        }
      } else {
        int mbase = m0 + wm * 64 + mf * 16 + lg * 4;
        int b = mbase >> 11, sbase = mbase & 2047;
        size_t idx0 = (((size_t)b * NH + nblk) * SEQ + sbase) * HD + nl;
        if (z == 0) {
#pragma unroll
          for (int r = 0; r < 4; ++r)
            outQ[idx0 + (size_t)r * HD] = f2bf(acc[mf][nf][r] + bv);
        } else if (z == 1) {
#pragma unroll
          for (int r = 0; r < 4; ++r) {
            float val = acc[mf][nf][r] + bv;
            outF[(size_t)8388608u + idx0 + (size_t)r * HD] = val;
            Kbf[idx0 + (size_t)r * HD] = f2bf(val);
          }
        } else {
          union { ushort u[4]; uint2 v; } p4;
#pragma unroll
          for (int r = 0; r < 4; ++r) {
            float val = acc[mf][nf][r] + bv;
            outF[(size_t)16777216u + idx0 + (size_t)r * HD] = val;
            p4.u[r] = f2bf(val);
          }
          // V^T (B,H,D,S): 8B packed store, 4 consecutive s
          *(uint2*)&vTb[(((size_t)b * NH + nblk) * HD + nl) * SEQ + sbase] = p4.v;
        }
      }
    }
  }
}

// ---------------- sliding-window flash attention ---------------------------
// block: (bh, qblk of 64). 4 waves x 16 q-rows. K-tiles of 64 keys.
// K/V^T staged bf16 via global_load_lds, double-buffered, counted vmcnt(8).
__global__ __launch_bounds__(256) void attn_kernel(
    const ushort* __restrict__ Qb, const ushort* __restrict__ Kb,
    const ushort* __restrict__ vT, ushort* __restrict__ ctx) {
  __shared__ __align__(16) ushort Kl[2][8192];  // [key][16 chunks], cs^=(key&7)
  __shared__ __align__(16) ushort Vt[2][8192];  // [d][8 chunks],   cs^=(d&7)
  __shared__ __align__(16) ushort Pl[4608];
  const int t = threadIdx.x;
  const int bh = blockIdx.x;
  const int q0 = blockIdx.y * 64;
  const int lane = t & 63, w = t >> 6;
  const int l15 = lane & 15, lg = lane >> 4;
  const int b = bh >> 4, h = bh & 15;
  const ushort* Qbase = Qb + (size_t)bh * SEQ * HD;
  const ushort* Kbase = Kb + (size_t)bh * SEQ * HD;
  const ushort* Vbase = vT + (size_t)bh * HD * SEQ;

  // per-thread gl16 sources (tile-invariant part; swizzle on global chunk)
  const ushort* kS[4];
  const ushort* vS[4];
#pragma unroll
  for (int p = 0; p < 4; ++p) {
    int s = p * 256 + t;
    int kr = s >> 4, kc = (s & 15) ^ (kr & 7);
    kS[p] = Kbase + kr * HD + kc * 8;
    int vr = s >> 3, vc = (s & 7) ^ (vr & 7);
    vS[p] = Vbase + vr * SEQ + vc * 8;
  }

#define ASTAGE(kt, buf)                                                  \
  {                                                                      \
    size_t ko = (size_t)(kt) * 8192, vo = (size_t)(kt) * 64;             \
    gl16(kS[0] + ko, &Kl[buf][(w * 64) * 8]);                            \
    gl16(kS[1] + ko, &Kl[buf][(256 + w * 64) * 8]);                      \
    gl16(kS[2] + ko, &Kl[buf][(512 + w * 64) * 8]);                      \
    gl16(kS[3] + ko, &Kl[buf][(768 + w * 64) * 8]);                      \
    gl16(vS[0] + vo, &Vt[buf][(w * 64) * 8]);                            \
    gl16(vS[1] + vo, &Vt[buf][(256 + w * 64) * 8]);                      \
    gl16(vS[2] + vo, &Vt[buf][(512 + w * 64) * 8]);                      \
    gl16(vS[3] + vo, &Vt[buf][(768 + w * 64) * 8]);                      \
  }

  bf16x8 aq[4];
#pragma unroll
  for (int ds = 0; ds < 4; ++ds)
    aq[ds] = *(const bf16x8*)&Qbase[(size_t)(q0 + w * 16 + l15) * HD + ds * 32 + lg * 8];

  f32x4 accc[8] = {};
  float mrow[4], lrow[4];
#pragma unroll
  for (int r = 0; r < 4; ++r) { mrow[r] = -1e30f; lrow[r] = 0.f; }

  int ktlo = (q0 - WIN + 1) >> 6;
  if (ktlo < 0) ktlo = 0;
  const int kthi = q0 >> 6;

  ASTAGE(ktlo, 0)
  {
    int t1 = (ktlo + 1 <= kthi) ? ktlo + 1 : kthi;
    ASTAGE(t1, 1)
  }

  for (int kt = ktlo; kt <= kthi; ++kt) {
    const int buf = (kt - ktlo) & 1;
    // own 8 newest loads (next tile) may stay in flight; tile kt drained.
    asm volatile("s_waitcnt vmcnt(8)" ::: "memory");
    BAR();

    f32x4 sacc[4] = {};
#pragma unroll
    for (int ds = 0; ds < 4; ++ds) {
#pragma unroll
      for (int kf = 0; kf < 4; ++kf) {
        int key = kf * 16 + l15;
        bf16x8 kb = *(const bf16x8*)&Kl[buf][key * 128 + (((ds * 4 + lg) ^ (key & 7)) * 8)];
        sacc[kf] = MFMA(aq[ds], kb, sacc[kf], 0, 0, 0);
      }
    }

    const float scale = 0.08838834764831845f;  // 1/sqrt(128)
    const float L2E = 1.4426950408889634f;
#pragma unroll
    for (int r = 0; r < 4; ++r) {
      int q = q0 + w * 16 + lg * 4 + r;
      float sv[4];
      float mx = -1e30f;
#pragma unroll
      for (int kf = 0; kf < 4; ++kf) {
        int key = kt * 64 + kf * 16 + l15;
        float s = sacc[kf][r] * scale;
        bool valid = (key <= q) && (key + WIN > q);
        s = valid ? s : -1e30f;
        sv[kf] = s;
        mx = fmaxf(mx, s);
      }
      mx = fmaxf(mx, __shfl_xor(mx, 1));
      mx = fmaxf(mx, __shfl_xor(mx, 2));
      mx = fmaxf(mx, __shfl_xor(mx, 4));
      mx = fmaxf(mx, __shfl_xor(mx, 8));
      float mnew = fmaxf(mrow[r], mx);
      float sf = exp2f((mrow[r] - mnew) * L2E);
      float ps = 0.f;
#pragma unroll
      for (int kf = 0; kf < 4; ++kf) {
        float p = (sv[kf] > -1e29f) ? exp2f((sv[kf] - mnew) * L2E) : 0.f;
        ps += p;
        Pl[w * 1152 + (lg * 4 + r) * 72 + kf * 16 + l15] = f2bf(p);
      }
      ps += __shfl_xor(ps, 1);
      ps += __shfl_xor(ps, 2);
      ps += __shfl_xor(ps, 4);
      ps += __shfl_xor(ps, 8);
      lrow[r] = lrow[r] * sf + ps;
      mrow[r] = mnew;
#pragma unroll
      for (int nf = 0; nf < 8; ++nf) accc[nf][r] *= sf;
    }

#pragma unroll
    for (int ks = 0; ks < 2; ++ks) {  // PV from V^T LDS
      bf16x8 pa = *(const bf16x8*)&Pl[w * 1152 + l15 * 72 + ks * 32 + lg * 8];
#pragma unroll
      for (int nf = 0; nf < 8; ++nf) {
        int vr = nf * 16 + l15;
        bf16x8 vb = *(const bf16x8*)&Vt[buf][vr * 64 + (((ks * 4 + lg) ^ (vr & 7)) * 8)];
        accc[nf] = MFMA(pa, vb, accc[nf], 0, 0, 0);
      }
    }

    BAR();  // all waves done reading buf before overwrite
    {
      int ts = (kt + 2 <= kthi) ? kt + 2 : kthi;  // tail restage: benign
      ASTAGE(ts, buf)
    }
  }
#undef ASTAGE

#pragma unroll
  for (int r = 0; r < 4; ++r) {
    int q = q0 + w * 16 + lg * 4 + r;
    float inv = 1.0f / lrow[r];
    size_t rowoff = ((size_t)b * SEQ + q) * EMB + (size_t)h * HD;
#pragma unroll
    for (int nf = 0; nf < 8; ++nf)
      ctx[rowoff + nf * 16 + l15] = f2bf(accc[nf][r] * inv);
  }
}

// ---------------------------------------------------------------------------
extern "C" void kernel_launch(void* const* d_in, const int* in_sizes, int n_in,
                              void* d_out, int out_size, void* d_ws, size_t ws_size,
                              hipStream_t stream) {
  const float* x  = (const float*)d_in[0];
  const float* Wq = (const float*)d_in[1];
  const float* bq = (const float*)d_in[2];
  const float* Wk = (const float*)d_in[3];
  const float* bk = (const float*)d_in[4];
  const float* Wv = (const float*)d_in[5];
  const float* bv = (const float*)d_in[6];
  const float* Wo = (const float*)d_in[7];
  const float* bo = (const float*)d_in[8];
  float* out = (float*)d_out;
  ushort* ws = (ushort*)d_ws;
  // ws (ushort): Wt 16777216 | Qb 8388608 | Kbf 8388608 | vTb 8388608 |
  //              xb/ctx 8388608 (aliased: xb dead after gemm<1>)
  ushort* Wt   = ws;
  ushort* Qb   = ws + 16777216;
  ushort* Kbf  = ws + 25165824;
  ushort* vTb  = ws + 33554432;
  ushort* xb   = ws + 41943040;
  ushort* ctxb = xb;

  xconv_kernel<<<4096, 256, 0, stream>>>(x, xb);
  wtrans_kernel<<<dim3(16, 64, 4), 256, 0, stream>>>(Wq, Wk, Wv, Wo, Wt);
  gemm_kernel<1><<<dim3(32, 16, 3), 256, 0, stream>>>(xb, Wt, bq, bk, bv, out,
                                                      Qb, Kbf, vTb);
  attn_kernel<<<dim3(32, 32), 256, 0, stream>>>(Qb, Kbf, vTb, ctxb);
  gemm_kernel<0><<<dim3(32, 16, 1), 256, 0, stream>>>(
      ctxb, Wt + (size_t)3 * 4194304, bo, nullptr, nullptr, out, nullptr,
      nullptr, nullptr);
}